// Round 1
// baseline (1017.112 us; speedup 1.0000x reference)
//
#include <hip/hip_runtime.h>
#include <math.h>

#define BDIM   131072
#define DDIM   1024
#define HDIM   128

__constant__ int c_perms[6][3] = {{0,1,2},{0,2,1},{1,0,2},{1,2,0},{2,0,1},{2,1,0}};

__device__ __forceinline__ float gelu_exact(float x) {
    return 0.5f * x * (1.0f + erff(x * 0.70710678118654752f));
}

// ---------------- K1: base = seq_embed @ W1[0:1024,:] + b1  (f32 tiled GEMM) ----------------
__global__ __launch_bounds__(256) void k1_gemm(const float* __restrict__ A,
                                               const float* __restrict__ W1,
                                               const float* __restrict__ b1,
                                               float* __restrict__ base)
{
    __shared__ float AsT[32][128];   // [k][m] transposed A tile
    __shared__ float Bs[32][128];    // [k][n]
    int t = threadIdx.x;
    int row0 = blockIdx.x * 128;
    int tx = t & 15, ty = t >> 4;

    float acc[8][8];
#pragma unroll
    for (int i = 0; i < 8; ++i)
#pragma unroll
        for (int j = 0; j < 8; ++j) acc[i][j] = 0.f;

    for (int kc = 0; kc < DDIM; kc += 32) {
        // load tiles to regs
        int r = t >> 1, kp = (t & 1) * 16;
        const float4* asrc = reinterpret_cast<const float4*>(&A[(size_t)(row0 + r) * DDIM + kc + kp]);
        float4 av[4];
#pragma unroll
        for (int i = 0; i < 4; ++i) av[i] = asrc[i];
        float4 bv[4];
#pragma unroll
        for (int p = 0; p < 4; ++p) {
            int f = t + p * 256; int k = f >> 5, n4 = f & 31;
            bv[p] = *reinterpret_cast<const float4*>(&W1[(size_t)(kc + k) * HDIM + n4 * 4]);
        }
        __syncthreads();   // previous compute done before overwrite
#pragma unroll
        for (int i = 0; i < 4; ++i) {
            int kk = kp + i * 4;
            AsT[kk + 0][r] = av[i].x; AsT[kk + 1][r] = av[i].y;
            AsT[kk + 2][r] = av[i].z; AsT[kk + 3][r] = av[i].w;
        }
#pragma unroll
        for (int p = 0; p < 4; ++p) {
            int f = t + p * 256; int k = f >> 5, n4 = f & 31;
            *reinterpret_cast<float4*>(&Bs[k][n4 * 4]) = bv[p];
        }
        __syncthreads();
#pragma unroll 4
        for (int kk = 0; kk < 32; ++kk) {
            float a[8], b[8];
            *reinterpret_cast<float4*>(&a[0]) = *reinterpret_cast<const float4*>(&AsT[kk][ty * 4]);
            *reinterpret_cast<float4*>(&a[4]) = *reinterpret_cast<const float4*>(&AsT[kk][64 + ty * 4]);
            *reinterpret_cast<float4*>(&b[0]) = *reinterpret_cast<const float4*>(&Bs[kk][tx * 4]);
            *reinterpret_cast<float4*>(&b[4]) = *reinterpret_cast<const float4*>(&Bs[kk][64 + tx * 4]);
#pragma unroll
            for (int i = 0; i < 8; ++i)
#pragma unroll
                for (int j = 0; j < 8; ++j)
                    acc[i][j] += a[i] * b[j];
        }
    }
    // epilogue: add b1, write base
#pragma unroll
    for (int i = 0; i < 8; ++i) {
        int m = (i < 4) ? (ty * 4 + i) : (64 + ty * 4 + (i - 4));
        float* orow = &base[(size_t)(row0 + m) * HDIM];
#pragma unroll
        for (int jh = 0; jh < 2; ++jh) {
            int n0 = jh * 64 + tx * 4;
            float4 v;
            v.x = acc[i][jh * 4 + 0] + b1[n0 + 0];
            v.y = acc[i][jh * 4 + 1] + b1[n0 + 1];
            v.z = acc[i][jh * 4 + 2] + b1[n0 + 2];
            v.w = acc[i][jh * 4 + 3] + b1[n0 + 3];
            *reinterpret_cast<float4*>(&orow[n0]) = v;
        }
    }
}

// ---------------- K2: 3-step recurrence, 32 lanes/row, 16 rows/block ----------------
#define NROWS 16
__global__ __launch_bounds__(512) void k2_steps(
    const float* __restrict__ base,   // may be null -> fallback
    const float* __restrict__ seq,
    const float* __restrict__ freq,
    const float* __restrict__ pres,
    const float* __restrict__ rmask,
    const int*   __restrict__ pidx,
    const float* __restrict__ W1,
    const float* __restrict__ b1,
    const float* __restrict__ W2,
    const float* __restrict__ b2,
    const float* __restrict__ W3,
    const float* __restrict__ b3,
    float* __restrict__ dec_f,
    float* __restrict__ dec_p,
    float* __restrict__ partials)
{
    __shared__ float W2s[128][128];
    __shared__ float W1es[12][128];
    __shared__ float h1s[NROWS][128];
    __shared__ float rowLoss[NROWS], rowMask[NROWS];

    int t = threadIdx.x;
#pragma unroll
    for (int p = 0; p < 8; ++p) {
        int f = t + p * 512; int k = f >> 5, n4 = f & 31;
        *reinterpret_cast<float4*>(&W2s[k][n4 * 4]) =
            *reinterpret_cast<const float4*>(&W2[(size_t)k * HDIM + n4 * 4]);
    }
    if (t < 384) {
        int k = t >> 5, n4 = t & 31;
        *reinterpret_cast<float4*>(&W1es[k][n4 * 4]) =
            *reinterpret_cast<const float4*>(&W1[(size_t)(1024 + k) * HDIM + n4 * 4]);
    }
    __syncthreads();

    int r = t >> 5;
    int lane = t & 31;
    int R = blockIdx.x * NROWS + r;
    int jA = lane * 2, jB = 64 + lane * 2;

    int pi = pidx[R];
    float ff[3], pp[3], mm[3];
#pragma unroll
    for (int q = 0; q < 3; ++q) {
        ff[q] = freq[(size_t)R * 3 + q];
        pp[q] = pres[(size_t)R * 3 + q];
        mm[q] = rmask[(size_t)R * 3 + q];
    }

    float bA0, bA1, bB0, bB1;
    if (base) {
        float2 vA = *reinterpret_cast<const float2*>(&base[(size_t)R * HDIM + jA]);
        float2 vB = *reinterpret_cast<const float2*>(&base[(size_t)R * HDIM + jB]);
        bA0 = vA.x; bA1 = vA.y; bB0 = vB.x; bB1 = vB.y;
    } else {
        bA0 = b1[jA]; bA1 = b1[jA + 1]; bB0 = b1[jB]; bB1 = b1[jB + 1];
        const float* srow = &seq[(size_t)R * DDIM];
        for (int k = 0; k < DDIM; ++k) {
            float sv = srow[k];
            const float* wr = &W1[(size_t)k * HDIM];
            bA0 += sv * wr[jA]; bA1 += sv * wr[jA + 1];
            bB0 += sv * wr[jB]; bB1 += sv * wr[jB + 1];
        }
    }

    float st[9];
#pragma unroll
    for (int i = 0; i < 9; ++i) st[i] = 0.f;
    float lossAcc = 0.f, maskAcc = 0.f;

    float b2A0 = b2[jA], b2A1 = b2[jA + 1], b2B0 = b2[jB], b2B1 = b2[jB + 1];
    float2 w3A0 = *reinterpret_cast<const float2*>(&W3[jA * 2]);
    float2 w3A1 = *reinterpret_cast<const float2*>(&W3[(jA + 1) * 2]);
    float2 w3B0 = *reinterpret_cast<const float2*>(&W3[jB * 2]);
    float2 w3B1 = *reinterpret_cast<const float2*>(&W3[(jB + 1) * 2]);
    float b30 = b3[0], b31 = b3[1];

    for (int s = 0; s < 3; ++s) {
        int ridx = c_perms[pi][s];
        float gt_f = (ridx == 0) ? ff[0] : ((ridx == 1) ? ff[1] : ff[2]);
        float gt_p = (ridx == 0) ? pp[0] : ((ridx == 1) ? pp[1] : pp[2]);
        float m    = (ridx == 0) ? mm[0] : ((ridx == 1) ? mm[1] : mm[2]);

        // layer 1: base + state part + one-hot row
        float pA0 = bA0, pA1 = bA1, pB0 = bB0, pB1 = bB1;
#pragma unroll
        for (int tt = 0; tt < 9; ++tt) {
            float sv = st[tt];
            float2 wA = *reinterpret_cast<const float2*>(&W1es[tt][jA]);
            float2 wB = *reinterpret_cast<const float2*>(&W1es[tt][jB]);
            pA0 += sv * wA.x; pA1 += sv * wA.y;
            pB0 += sv * wB.x; pB1 += sv * wB.y;
        }
        {
            float2 wA = *reinterpret_cast<const float2*>(&W1es[9 + ridx][jA]);
            float2 wB = *reinterpret_cast<const float2*>(&W1es[9 + ridx][jB]);
            pA0 += wA.x; pA1 += wA.y; pB0 += wB.x; pB1 += wB.y;
        }
        pA0 = gelu_exact(pA0); pA1 = gelu_exact(pA1);
        pB0 = gelu_exact(pB0); pB1 = gelu_exact(pB1);
        *reinterpret_cast<float2*>(&h1s[r][jA]) = make_float2(pA0, pA1);
        *reinterpret_cast<float2*>(&h1s[r][jB]) = make_float2(pB0, pB1);
        // same-wave LDS: DS ops are in-order per wave; compiler inserts lgkmcnt waits

        // layer 2
        float aA0 = b2A0, aA1 = b2A1, aB0 = b2B0, aB1 = b2B1;
        for (int k = 0; k < HDIM; ++k) {
            float hv = h1s[r][k];
            float2 wA = *reinterpret_cast<const float2*>(&W2s[k][jA]);
            float2 wB = *reinterpret_cast<const float2*>(&W2s[k][jB]);
            aA0 += hv * wA.x; aA1 += hv * wA.y;
            aB0 += hv * wB.x; aB1 += hv * wB.y;
        }
        aA0 = gelu_exact(aA0); aA1 = gelu_exact(aA1);
        aB0 = gelu_exact(aB0); aB1 = gelu_exact(aB1);

        // layer 3 partials + butterfly reduce over 32 lanes
        float p0 = aA0 * w3A0.x + aA1 * w3A1.x + aB0 * w3B0.x + aB1 * w3B1.x;
        float p1 = aA0 * w3A0.y + aA1 * w3A1.y + aB0 * w3B0.y + aB1 * w3B1.y;
#pragma unroll
        for (int mk = 1; mk <= 16; mk <<= 1) {
            p0 += __shfl_xor(p0, mk);
            p1 += __shfl_xor(p1, mk);
        }
        float pf = p0 + b30;
        float z  = p1 + b31;

        float d = pf - gt_f;
        float fl = d * d * m;
        float pl = (fmaxf(z, 0.f) - z * gt_p + log1pf(expf(-fabsf(z)))) * m;
        lossAcc += fl + pl;
        maskAcc += m;

        bool msk = m > 0.5f;
        float act_f = msk ? pf : gt_f;
        float act_p = msk ? (1.f / (1.f + expf(-z))) : gt_p;
#pragma unroll
        for (int q = 0; q < 3; ++q) {   // static-indexed state update (no scratch)
            if (q == ridx) { st[q * 3 + 0] = act_f; st[q * 3 + 1] = act_p; st[q * 3 + 2] = 1.f; }
        }
        if (lane == 0) {
            dec_f[(size_t)R * 3 + ridx] = act_f;
            dec_p[(size_t)R * 3 + ridx] = act_p;
        }
    }
    if (lane == 0) { rowLoss[r] = lossAcc; rowMask[r] = maskAcc; }
    __syncthreads();
    if (t == 0) {
        float ls = 0.f, ms = 0.f;
        for (int i = 0; i < NROWS; ++i) { ls += rowLoss[i]; ms += rowMask[i]; }
        partials[2 * (size_t)blockIdx.x]     = ls;
        partials[2 * (size_t)blockIdx.x + 1] = ms;
    }
}

// ---------------- K3: deterministic loss reduction ----------------
__global__ __launch_bounds__(256) void k3_reduce(const float* __restrict__ partials,
                                                 int nb, float* __restrict__ out)
{
    __shared__ float sl[256], sm[256];
    int t = threadIdx.x;
    float ls = 0.f, ms = 0.f;
    for (int i = t; i < nb; i += 256) { ls += partials[2 * i]; ms += partials[2 * i + 1]; }
    sl[t] = ls; sm[t] = ms;
    __syncthreads();
    for (int s = 128; s > 0; s >>= 1) {
        if (t < s) { sl[t] += sl[t + s]; sm[t] += sm[t + s]; }
        __syncthreads();
    }
    if (t == 0) out[0] = sl[0] / (sm[0] + 1e-8f);
}

extern "C" void kernel_launch(void* const* d_in, const int* in_sizes, int n_in,
                              void* d_out, int out_size, void* d_ws, size_t ws_size,
                              hipStream_t stream) {
    const float* seq   = (const float*)d_in[0];
    const float* freq  = (const float*)d_in[1];
    const float* pres  = (const float*)d_in[2];
    const float* rmask = (const float*)d_in[3];
    const int*   pidx  = (const int*)d_in[4];
    const float* W1    = (const float*)d_in[5];
    const float* b1    = (const float*)d_in[6];
    const float* W2    = (const float*)d_in[7];
    const float* b2    = (const float*)d_in[8];
    const float* W3    = (const float*)d_in[9];
    const float* b3    = (const float*)d_in[10];

    int B = in_sizes[4];                 // perm_idx count
    float* out   = (float*)d_out;
    float* dec_f = out + 1;
    float* dec_p = out + 1 + (size_t)B * 3;

    int nblocks2 = B / NROWS;
    size_t partBytes = (size_t)nblocks2 * 2 * sizeof(float);
    size_t baseOff   = (partBytes + 255) & ~(size_t)255;
    size_t needBase  = baseOff + (size_t)B * HDIM * sizeof(float);

    float* partials = (float*)d_ws;
    float* base = (ws_size >= needBase) ? (float*)((char*)d_ws + baseOff) : nullptr;

    if (base) {
        k1_gemm<<<B / 128, 256, 0, stream>>>(seq, W1, b1, base);
    }
    k2_steps<<<nblocks2, 512, 0, stream>>>(base, seq, freq, pres, rmask, pidx,
                                           W1, b1, W2, b2, W3, b3,
                                           dec_f, dec_p, partials);
    k3_reduce<<<1, 256, 0, stream>>>(partials, nblocks2, out);
}

// Round 2
// 387.153 us; speedup vs baseline: 2.6272x; 2.6272x over previous
//
#include <hip/hip_runtime.h>
#include <math.h>

#define BTOT 131072
#define DDIM 1024
#define HDIM 128

typedef float  f32x4  __attribute__((ext_vector_type(4)));
typedef __bf16 bf16x8 __attribute__((ext_vector_type(8)));

union AFrag { ushort u[8]; bf16x8 v; };

__constant__ int c_perms[6][3] = {{0,1,2},{0,2,1},{1,0,2},{1,2,0},{2,0,1},{2,1,0}};

__device__ __forceinline__ ushort f2bf(float f){
    uint u = __float_as_uint(f);
    u += 0x7FFFu + ((u>>16)&1u);     // RNE
    return (ushort)(u>>16);
}
__device__ __forceinline__ float bf2f(ushort s){
    return __uint_as_float(((uint)s)<<16);
}
__device__ __forceinline__ float gelu_exact(float x){
    return 0.5f * x * (1.0f + erff(x * 0.70710678118654752f));
}

// ---------------- K0: build pre-swizzled bf16 images of W1[:1024] (transposed, per-64k tiles) and W2 (transposed) ----------------
// w1t: 16 tiles t of [128 n][64 kk] bf16, byte(n,kk) = t*16384 + n*128 + ((kk*2) ^ ((n&7)<<4))
// w2t: [128 n][128 k]  bf16, byte(n,k)  = n*256 + ((k*2) ^ ((n&7)<<4))
__global__ __launch_bounds__(256) void k0_prep(const float* __restrict__ W1,
                                               const float* __restrict__ W2,
                                               ushort* __restrict__ w1t,
                                               ushort* __restrict__ w2t)
{
    int i = blockIdx.x * 256 + threadIdx.x;
    if (i < DDIM * HDIM) {
        int k = i >> 7, n = i & 127;
        ushort b = f2bf(W1[(size_t)k * HDIM + n]);
        int tt = k >> 6, kk = k & 63;
        size_t off = (size_t)tt * 16384 + (size_t)n * 128 + (size_t)(((kk * 2) ^ ((n & 7) << 4)));
        w1t[off >> 1] = b;
    } else if (i < DDIM * HDIM + HDIM * HDIM) {
        int j = i - DDIM * HDIM;
        int k = j >> 7, n = j & 127;
        ushort b = f2bf(W2[(size_t)k * HDIM + n]);
        size_t off = (size_t)n * 256 + (size_t)(((k * 2) ^ ((n & 7) << 4)));
        w2t[off >> 1] = b;
    }
}

// ---------------- K1: base = bf16( seq @ W1[:1024] + b1 )  via 16x16x32 bf16 MFMA ----------------
__global__ __launch_bounds__(256) void k1_gemm(const float* __restrict__ seq,
                                               const ushort* __restrict__ w1t,
                                               const float* __restrict__ b1,
                                               ushort* __restrict__ baseo)
{
    __shared__ char As[16384];   // [128 m][64 kk] bf16, byte ^= (m&7)<<4
    __shared__ char Bs[16384];   // [128 n][64 kk] bf16, byte ^= (n&7)<<4
    const int t = threadIdx.x;
    const int wid = t >> 6, lane = t & 63;
    const int g = lane >> 4, ln = lane & 15;
    const size_t row0 = (size_t)blockIdx.x * 128;

    f32x4 acc[2][8];
#pragma unroll
    for (int m = 0; m < 2; ++m)
#pragma unroll
        for (int n = 0; n < 8; ++n) acc[m][n] = (f32x4){0.f, 0.f, 0.f, 0.f};

    for (int t16 = 0; t16 < 16; ++t16) {
        const int kc = t16 * 64;
        float4 av[8];
#pragma unroll
        for (int i = 0; i < 8; ++i) {
            int row = i * 16 + (t >> 4);
            av[i] = *reinterpret_cast<const float4*>(&seq[(row0 + row) * DDIM + kc + (t & 15) * 4]);
        }
        uint4 bv[4];
#pragma unroll
        for (int i = 0; i < 4; ++i)
            bv[i] = *reinterpret_cast<const uint4*>((const char*)w1t + (size_t)t16 * 16384 + t * 16 + i * 4096);

        __syncthreads();   // previous tile's reads done
#pragma unroll
        for (int i = 0; i < 8; ++i) {
            int row = i * 16 + (t >> 4);
            uint lo = (uint)f2bf(av[i].x) | ((uint)f2bf(av[i].y) << 16);
            uint hi = (uint)f2bf(av[i].z) | ((uint)f2bf(av[i].w) << 16);
            uint2 w = make_uint2(lo, hi);
            *reinterpret_cast<uint2*>(As + row * 128 + ((((t & 15) * 8)) ^ ((row & 7) << 4))) = w;
        }
#pragma unroll
        for (int i = 0; i < 4; ++i)
            *reinterpret_cast<uint4*>(Bs + t * 16 + i * 4096) = bv[i];
        __syncthreads();

#pragma unroll
        for (int half = 0; half < 2; ++half) {
            const int kb = half * 64 + g * 16;
            const int rA0 = wid * 32 + ln, rA1 = rA0 + 16;
            bf16x8 a0 = *reinterpret_cast<const bf16x8*>(As + rA0 * 128 + (kb ^ ((rA0 & 7) << 4)));
            bf16x8 a1 = *reinterpret_cast<const bf16x8*>(As + rA1 * 128 + (kb ^ ((rA1 & 7) << 4)));
#pragma unroll
            for (int nf = 0; nf < 8; ++nf) {
                const int n = nf * 16 + ln;
                bf16x8 bb = *reinterpret_cast<const bf16x8*>(Bs + n * 128 + (kb ^ ((n & 7) << 4)));
                acc[0][nf] = __builtin_amdgcn_mfma_f32_16x16x32_bf16(a0, bb, acc[0][nf], 0, 0, 0);
                acc[1][nf] = __builtin_amdgcn_mfma_f32_16x16x32_bf16(a1, bb, acc[1][nf], 0, 0, 0);
            }
        }
    }
    float b1v[8];
#pragma unroll
    for (int nf = 0; nf < 8; ++nf) b1v[nf] = b1[nf * 16 + ln];
#pragma unroll
    for (int mf = 0; mf < 2; ++mf)
#pragma unroll
        for (int nf = 0; nf < 8; ++nf)
#pragma unroll
            for (int r = 0; r < 4; ++r) {
                int row = wid * 32 + mf * 16 + g * 4 + r;   // C/D: col=lane&15, row=(lane>>4)*4+reg [m89]
                int col = nf * 16 + ln;
                baseo[(row0 + row) * HDIM + col] = f2bf(acc[mf][nf][r] + b1v[nf]);
            }
}

// ---------------- K2: 3-step recurrence; 4 waves x 16 rows; layer2 via MFMA, no barriers in step loop ----------------
__global__ __launch_bounds__(256) void k2_steps(
    const ushort* __restrict__ basei,   // [B][128] bf16 (includes b1)
    const ushort* __restrict__ w2t,     // swizzled W2^T image, 32KB
    const float* __restrict__ freq,
    const float* __restrict__ pres,
    const float* __restrict__ rmask,
    const int*   __restrict__ pidx,
    const float* __restrict__ W1,       // for rows 1024..1035 (state + one-hot)
    const float* __restrict__ b2,
    const float* __restrict__ W3,
    const float* __restrict__ b3,
    float* __restrict__ dec_f,
    float* __restrict__ dec_p,
    float* __restrict__ partials)
{
    __shared__ char  W2s[32768];
    __shared__ float W1es[12][128];
    __shared__ float stl[64][2];     // per-row (act_f, act_p) exchange, wave-private rows
    __shared__ float redl[8];

    const int t = threadIdx.x;
    const int wid = t >> 6, lane = t & 63;
    const int g = lane >> 4, ln = lane & 15;

#pragma unroll
    for (int i = 0; i < 8; ++i) {
        uint4 v = *reinterpret_cast<const uint4*>((const char*)w2t + t * 16 + i * 4096);
        *reinterpret_cast<uint4*>(W2s + t * 16 + i * 4096) = v;
    }
    for (int i = t; i < 12 * 128; i += 256)
        W1es[i >> 7][i & 127] = W1[(size_t)(DDIM + (i >> 7)) * HDIM + (i & 127)];
    __syncthreads();

    const int rowLocal = wid * 16 + ln;                 // h1 row this lane computes
    const size_t R_h = (size_t)blockIdx.x * 64 + rowLocal;
    const int pidx_h = pidx[R_h];

    float basef[32];                                     // cols c = ks*32 + g*8 + j
    {
        const ushort* brow = basei + R_h * HDIM;
#pragma unroll
        for (int ks = 0; ks < 4; ++ks) {
            uint4 v = *reinterpret_cast<const uint4*>(brow + ks * 32 + g * 8);
            const ushort* pu = reinterpret_cast<const ushort*>(&v);
#pragma unroll
            for (int j = 0; j < 8; ++j) basef[ks * 8 + j] = bf2f(pu[j]);
        }
    }
    float scon[32];                                      // incremental state @ W1e contribution
#pragma unroll
    for (int i = 0; i < 32; ++i) scon[i] = 0.f;

    const bool owner = (ln < 4);
    const int rloc_own = wid * 16 + g * 4 + ln;
    const size_t R_own = (size_t)blockIdx.x * 64 + rloc_own;
    int pio = 0;
    float ffo[3] = {0,0,0}, ppo[3] = {0,0,0}, mmo[3] = {0,0,0};
    if (owner) {
        pio = pidx[R_own];
#pragma unroll
        for (int q = 0; q < 3; ++q) {
            ffo[q] = freq[R_own * 3 + q];
            ppo[q] = pres[R_own * 3 + q];
            mmo[q] = rmask[R_own * 3 + q];
        }
    }
    float b2v[8], w30[8], w31[8];
#pragma unroll
    for (int nf = 0; nf < 8; ++nf) {
        b2v[nf] = b2[nf * 16 + ln];
        w30[nf] = W3[(nf * 16 + ln) * 2 + 0];
        w31[nf] = W3[(nf * 16 + ln) * 2 + 1];
    }
    const float b30 = b3[0], b31 = b3[1];

    float lossAcc = 0.f, maskAcc = 0.f;

    for (int s = 0; s < 3; ++s) {
        const int ridx_h = c_perms[pidx_h][s];
        // ---- layer 1 build + gelu + pack into A fragments
        AFrag afr[4];
#pragma unroll
        for (int ks = 0; ks < 4; ++ks) {
            const float* ohp = &W1es[9 + ridx_h][ks * 32 + g * 8];
            f32x4 o0 = *reinterpret_cast<const f32x4*>(ohp);
            f32x4 o1 = *reinterpret_cast<const f32x4*>(ohp + 4);
            float h[8];
#pragma unroll
            for (int j = 0; j < 4; ++j) {
                h[j]     = basef[ks * 8 + j]     + scon[ks * 8 + j]     + o0[j];
                h[4 + j] = basef[ks * 8 + 4 + j] + scon[ks * 8 + 4 + j] + o1[j];
            }
#pragma unroll
            for (int j = 0; j < 8; ++j) afr[ks].u[j] = f2bf(gelu_exact(h[j]));
        }
        // ---- layer 2: MFMA over K=128
        f32x4 acc[8];
#pragma unroll
        for (int nf = 0; nf < 8; ++nf) acc[nf] = (f32x4){0.f, 0.f, 0.f, 0.f};
#pragma unroll
        for (int ks = 0; ks < 4; ++ks) {
#pragma unroll
            for (int nf = 0; nf < 8; ++nf) {
                const int n = nf * 16 + ln;
                bf16x8 bb = *reinterpret_cast<const bf16x8*>(W2s + n * 256 + ((ks * 64 + g * 16) ^ ((n & 7) << 4)));
                acc[nf] = __builtin_amdgcn_mfma_f32_16x16x32_bf16(afr[ks].v, bb, acc[nf], 0, 0, 0);
            }
        }
        // ---- h2 gelu + layer 3 partials (rows g*4+r, cols nf*16+ln)
        float p0[4] = {0, 0, 0, 0}, p1[4] = {0, 0, 0, 0};
#pragma unroll
        for (int nf = 0; nf < 8; ++nf) {
#pragma unroll
            for (int r = 0; r < 4; ++r) {
                float h2 = gelu_exact(acc[nf][r] + b2v[nf]);
                p0[r] += h2 * w30[nf];
                p1[r] += h2 * w31[nf];
            }
        }
#pragma unroll
        for (int mk = 1; mk < 16; mk <<= 1) {
#pragma unroll
            for (int r = 0; r < 4; ++r) {
                p0[r] += __shfl_xor(p0[r], mk);
                p1[r] += __shfl_xor(p1[r], mk);
            }
        }
        // ---- per-row epilogue on owner lanes (rows g*4 + ln, ln<4)
        if (owner) {
            const int ridx_o = c_perms[pio][s];
            float pf = ((ln == 0) ? p0[0] : (ln == 1) ? p0[1] : (ln == 2) ? p0[2] : p0[3]) + b30;
            float z  = ((ln == 0) ? p1[0] : (ln == 1) ? p1[1] : (ln == 2) ? p1[2] : p1[3]) + b31;
            float gt_f = (ridx_o == 0) ? ffo[0] : (ridx_o == 1) ? ffo[1] : ffo[2];
            float gt_p = (ridx_o == 0) ? ppo[0] : (ridx_o == 1) ? ppo[1] : ppo[2];
            float m    = (ridx_o == 0) ? mmo[0] : (ridx_o == 1) ? mmo[1] : mmo[2];
            float d = pf - gt_f;
            float pl = (fmaxf(z, 0.f) - z * gt_p + log1pf(expf(-fabsf(z)))) * m;
            lossAcc += d * d * m + pl;
            maskAcc += m;
            bool msk = m > 0.5f;
            float act_f = msk ? pf : gt_f;
            float act_p = msk ? (1.f / (1.f + expf(-z))) : gt_p;
            stl[rloc_own][0] = act_f;
            stl[rloc_own][1] = act_p;
            dec_f[R_own * 3 + ridx_o] = act_f;
            dec_p[R_own * 3 + ridx_o] = act_p;
        }
        // ---- incremental state contribution update (same wave: DS ops in order)
        if (s < 2) {
            float af = stl[rowLocal][0];
            float ap = stl[rowLocal][1];
            const float* w0r = &W1es[ridx_h * 3 + 0][0];
            const float* w1r = &W1es[ridx_h * 3 + 1][0];
            const float* w2r = &W1es[ridx_h * 3 + 2][0];
#pragma unroll
            for (int ks = 0; ks < 4; ++ks) {
                const int c0 = ks * 32 + g * 8;
                f32x4 a0 = *reinterpret_cast<const f32x4*>(w0r + c0);
                f32x4 a1 = *reinterpret_cast<const f32x4*>(w0r + c0 + 4);
                f32x4 b0 = *reinterpret_cast<const f32x4*>(w1r + c0);
                f32x4 b1x = *reinterpret_cast<const f32x4*>(w1r + c0 + 4);
                f32x4 c0v = *reinterpret_cast<const f32x4*>(w2r + c0);
                f32x4 c1v = *reinterpret_cast<const f32x4*>(w2r + c0 + 4);
#pragma unroll
                for (int j = 0; j < 4; ++j) {
                    scon[ks * 8 + j]     += af * a0[j] + ap * b0[j]  + c0v[j];
                    scon[ks * 8 + 4 + j] += af * a1[j] + ap * b1x[j] + c1v[j];
                }
            }
        }
    }
    // ---- deterministic loss reduction
#pragma unroll
    for (int mk = 1; mk < 64; mk <<= 1) {
        lossAcc += __shfl_xor(lossAcc, mk);
        maskAcc += __shfl_xor(maskAcc, mk);
    }
    if (lane == 0) { redl[wid * 2] = lossAcc; redl[wid * 2 + 1] = maskAcc; }
    __syncthreads();
    if (t == 0) {
        float ls = 0.f, ms = 0.f;
#pragma unroll
        for (int w = 0; w < 4; ++w) { ls += redl[w * 2]; ms += redl[w * 2 + 1]; }
        partials[2 * (size_t)blockIdx.x]     = ls;
        partials[2 * (size_t)blockIdx.x + 1] = ms;
    }
}

// ---------------- K3: deterministic final reduction ----------------
__global__ __launch_bounds__(256) void k3_reduce(const float* __restrict__ partials,
                                                 int nb, float* __restrict__ out)
{
    __shared__ float sl[256], sm[256];
    int t = threadIdx.x;
    float ls = 0.f, ms = 0.f;
    for (int i = t; i < nb; i += 256) { ls += partials[2 * i]; ms += partials[2 * i + 1]; }
    sl[t] = ls; sm[t] = ms;
    __syncthreads();
    for (int s = 128; s > 0; s >>= 1) {
        if (t < s) { sl[t] += sl[t + s]; sm[t] += sm[t + s]; }
        __syncthreads();
    }
    if (t == 0) out[0] = sl[0] / (sm[0] + 1e-8f);
}

extern "C" void kernel_launch(void* const* d_in, const int* in_sizes, int n_in,
                              void* d_out, int out_size, void* d_ws, size_t ws_size,
                              hipStream_t stream) {
    const float* seq   = (const float*)d_in[0];
    const float* freq  = (const float*)d_in[1];
    const float* pres  = (const float*)d_in[2];
    const float* rmask = (const float*)d_in[3];
    const int*   pidx  = (const int*)d_in[4];
    const float* W1    = (const float*)d_in[5];
    const float* b1    = (const float*)d_in[6];
    const float* W2    = (const float*)d_in[7];
    const float* b2    = (const float*)d_in[8];
    const float* W3    = (const float*)d_in[9];
    const float* b3    = (const float*)d_in[10];

    int B = in_sizes[4];
    float* out   = (float*)d_out;
    float* dec_f = out + 1;
    float* dec_p = out + 1 + (size_t)B * 3;

    char* ws = (char*)d_ws;
    float*  partials = (float*)ws;                                   // 16 KB (2048*2*4)
    ushort* w1t  = (ushort*)(ws + 16384);                            // 256 KB
    ushort* w2t  = (ushort*)(ws + 16384 + 262144);                   // 32 KB
    ushort* base = (ushort*)(ws + 16384 + 262144 + 32768);           // 33.5 MB

    k0_prep<<<(DDIM * HDIM + HDIM * HDIM + 255) / 256, 256, 0, stream>>>(W1, W2, w1t, w2t);
    k1_gemm<<<B / 128, 256, 0, stream>>>(seq, w1t, b1, base);
    k2_steps<<<B / 64, 256, 0, stream>>>(base, w2t, freq, pres, rmask, pidx,
                                         W1, b2, W3, b3, dec_f, dec_p, partials);
    k3_reduce<<<1, 256, 0, stream>>>(partials, B / 64, out);
}

// Round 3
// 333.348 us; speedup vs baseline: 3.0512x; 1.1614x over previous
//
#include <hip/hip_runtime.h>
#include <math.h>

#define BTOT 131072
#define DDIM 1024
#define HDIM 128

typedef float  f32x4  __attribute__((ext_vector_type(4)));
typedef __bf16 bf16x4 __attribute__((ext_vector_type(4)));
typedef __bf16 bf16x8 __attribute__((ext_vector_type(8)));

union AFrag { __bf16 h[8]; bf16x8 v; };
union BF2U { __bf16 h; ushort u; };

__constant__ int c_perms[6][3] = {{0,1,2},{0,2,1},{1,0,2},{1,2,0},{2,0,1},{2,1,0}};

__device__ __forceinline__ ushort f2bf(float f){
    BF2U c; c.h = (__bf16)f; return c.u;
}
// branch-free gelu: Abramowitz-Stegun 7.1.26 erf (|err| < 1.5e-7), HW exp
__device__ __forceinline__ float gelu_fast(float x){
    float a = fabsf(x) * 0.70710678118654752f;
    float t = __frcp_rn(fmaf(0.3275911f, a, 1.0f));
    float p = t * fmaf(t, fmaf(t, fmaf(t, fmaf(t, 1.061405429f, -1.453152027f),
                 1.421413741f), -0.284496736f), 0.254829592f);
    float y = 1.0f - p * __expf(-a * a);
    float er = copysignf(y, x);
    return 0.5f * x * (1.0f + er);
}

// ---------------- K0: build pre-swizzled bf16 images of W1[:1024] (transposed tiles) and W2 (transposed) ----------------
// w1t: 16 tiles t of [128 n][64 kk] bf16, byte(n,kk) = t*16384 + n*128 + ((kk*2) ^ ((n&7)<<4))
// w2t: [128 n][128 k]  bf16, byte(n,k)  = n*256 + ((k*2) ^ ((n&7)<<4))
__global__ __launch_bounds__(256) void k0_prep(const float* __restrict__ W1,
                                               const float* __restrict__ W2,
                                               ushort* __restrict__ w1t,
                                               ushort* __restrict__ w2t)
{
    int i = blockIdx.x * 256 + threadIdx.x;
    if (i < DDIM * HDIM) {
        int k = i >> 7, n = i & 127;
        ushort b = f2bf(W1[(size_t)k * HDIM + n]);
        int tt = k >> 6, kk = k & 63;
        size_t off = (size_t)tt * 16384 + (size_t)n * 128 + (size_t)(((kk * 2) ^ ((n & 7) << 4)));
        w1t[off >> 1] = b;
    } else if (i < DDIM * HDIM + HDIM * HDIM) {
        int j = i - DDIM * HDIM;
        int k = j >> 7, n = j & 127;
        ushort b = f2bf(W2[(size_t)k * HDIM + n]);
        size_t off = (size_t)n * 256 + (size_t)(((k * 2) ^ ((n & 7) << 4)));
        w2t[off >> 1] = b;
    }
}

// ---------------- K1: base = bf16( seq @ W1[:1024] + b1 )  via 16x16x32 bf16 MFMA, prefetch-pipelined ----------------
__global__ __launch_bounds__(256) void k1_gemm(const float* __restrict__ seq,
                                               const ushort* __restrict__ w1t,
                                               const float* __restrict__ b1,
                                               ushort* __restrict__ baseo)
{
    __shared__ char As[16384];   // [128 m][64 kk] bf16, byte ^= (m&7)<<4
    __shared__ char Bs[16384];   // [128 n][64 kk] bf16, byte ^= (n&7)<<4
    const int t = threadIdx.x;
    const int wid = t >> 6, lane = t & 63;
    const int g = lane >> 4, ln = lane & 15;
    const size_t row0 = (size_t)blockIdx.x * 128;

    f32x4 acc[2][8];
#pragma unroll
    for (int m = 0; m < 2; ++m)
#pragma unroll
        for (int n = 0; n < 8; ++n) acc[m][n] = (f32x4){0.f, 0.f, 0.f, 0.f};

    float4 av[8];
    uint4  bv[4];
    const int arow = t >> 4, acolb = (t & 15) * 4;   // A-load coords

    // prologue: issue loads for tile 0
#pragma unroll
    for (int i = 0; i < 8; ++i)
        av[i] = *reinterpret_cast<const float4*>(&seq[(row0 + i * 16 + arow) * DDIM + acolb]);
#pragma unroll
    for (int i = 0; i < 4; ++i)
        bv[i] = *reinterpret_cast<const uint4*>((const char*)w1t + t * 16 + i * 4096);

    for (int t16 = 0; t16 < 16; ++t16) {
        __syncthreads();   // readers of previous tile done
#pragma unroll
        for (int i = 0; i < 8; ++i) {
            int row = i * 16 + arow;
            bf16x4 hv;
            hv[0] = (__bf16)av[i].x; hv[1] = (__bf16)av[i].y;
            hv[2] = (__bf16)av[i].z; hv[3] = (__bf16)av[i].w;
            *reinterpret_cast<bf16x4*>(As + row * 128 + ((acolb * 2) ^ ((row & 7) << 4))) = hv;
        }
#pragma unroll
        for (int i = 0; i < 4; ++i)
            *reinterpret_cast<uint4*>(Bs + t * 16 + i * 4096) = bv[i];
        __syncthreads();

        // issue prefetch for next tile; flies during MFMA compute below
        if (t16 < 15) {
            const int kc = (t16 + 1) * 64;
#pragma unroll
            for (int i = 0; i < 8; ++i)
                av[i] = *reinterpret_cast<const float4*>(&seq[(row0 + i * 16 + arow) * DDIM + kc + acolb]);
#pragma unroll
            for (int i = 0; i < 4; ++i)
                bv[i] = *reinterpret_cast<const uint4*>((const char*)w1t + (size_t)(t16 + 1) * 16384 + t * 16 + i * 4096);
        }

#pragma unroll
        for (int half = 0; half < 2; ++half) {
            const int kb = half * 64 + g * 16;
            const int rA0 = wid * 32 + ln, rA1 = rA0 + 16;
            bf16x8 a0 = *reinterpret_cast<const bf16x8*>(As + rA0 * 128 + (kb ^ ((rA0 & 7) << 4)));
            bf16x8 a1 = *reinterpret_cast<const bf16x8*>(As + rA1 * 128 + (kb ^ ((rA1 & 7) << 4)));
#pragma unroll
            for (int nf = 0; nf < 8; ++nf) {
                const int n = nf * 16 + ln;
                bf16x8 bb = *reinterpret_cast<const bf16x8*>(Bs + n * 128 + (kb ^ ((n & 7) << 4)));
                acc[0][nf] = __builtin_amdgcn_mfma_f32_16x16x32_bf16(a0, bb, acc[0][nf], 0, 0, 0);
                acc[1][nf] = __builtin_amdgcn_mfma_f32_16x16x32_bf16(a1, bb, acc[1][nf], 0, 0, 0);
            }
        }
    }
    float b1v[8];
#pragma unroll
    for (int nf = 0; nf < 8; ++nf) b1v[nf] = b1[nf * 16 + ln];
#pragma unroll
    for (int mf = 0; mf < 2; ++mf)
#pragma unroll
        for (int nf = 0; nf < 8; ++nf)
#pragma unroll
            for (int r = 0; r < 4; ++r) {
                int row = wid * 32 + mf * 16 + g * 4 + r;   // C/D: col=lane&15, row=(lane>>4)*4+reg [m89]
                int col = nf * 16 + ln;
                baseo[(row0 + row) * HDIM + col] = f2bf(acc[mf][nf][r] + b1v[nf]);
            }
}

// ---------------- K2: 3-step recurrence; 4 waves x 16 rows; layer2 via MFMA, no barriers in step loop ----------------
__global__ __launch_bounds__(256) void k2_steps(
    const ushort* __restrict__ basei,   // [B][128] bf16 (includes b1)
    const ushort* __restrict__ w2t,     // swizzled W2^T image, 32KB
    const float* __restrict__ freq,
    const float* __restrict__ pres,
    const float* __restrict__ rmask,
    const int*   __restrict__ pidx,
    const float* __restrict__ W1,       // rows 1024..1035 (state + one-hot)
    const float* __restrict__ b2,
    const float* __restrict__ W3,
    const float* __restrict__ b3,
    float* __restrict__ dec_f,
    float* __restrict__ dec_p,
    float* __restrict__ partials)
{
    __shared__ char  W2s[32768];
    __shared__ float W1es[12][128];
    __shared__ float stl[64][2];     // per-row (act_f, act_p) exchange, wave-private rows
    __shared__ float redl[8];

    const int t = threadIdx.x;
    const int wid = t >> 6, lane = t & 63;
    const int g = lane >> 4, ln = lane & 15;

#pragma unroll
    for (int i = 0; i < 8; ++i) {
        uint4 v = *reinterpret_cast<const uint4*>((const char*)w2t + t * 16 + i * 4096);
        *reinterpret_cast<uint4*>(W2s + t * 16 + i * 4096) = v;
    }
    for (int i = t; i < 12 * 128; i += 256)
        W1es[i >> 7][i & 127] = W1[(size_t)(DDIM + (i >> 7)) * HDIM + (i & 127)];
    __syncthreads();

    const int rowLocal = wid * 16 + ln;                 // h1 row this lane computes (cols split by g)
    const size_t R_h = (size_t)blockIdx.x * 64 + rowLocal;
    const int pidx_h = pidx[R_h];

    float basef[32];                                     // cols c = ks*32 + g*8 + j
    {
        const ushort* brow = basei + R_h * HDIM;
#pragma unroll
        for (int ks = 0; ks < 4; ++ks) {
            bf16x8 v = *reinterpret_cast<const bf16x8*>(brow + ks * 32 + g * 8);
#pragma unroll
            for (int j = 0; j < 8; ++j) basef[ks * 8 + j] = (float)v[j];
        }
    }
    float scon[32];                                      // incremental state @ W1e contribution
#pragma unroll
    for (int i = 0; i < 32; ++i) scon[i] = 0.f;

    const bool owner = (ln < 4);
    const int rloc_own = wid * 16 + g * 4 + ln;
    const size_t R_own = (size_t)blockIdx.x * 64 + rloc_own;
    int pio = 0;
    float ffo[3] = {0,0,0}, ppo[3] = {0,0,0}, mmo[3] = {0,0,0};
    if (owner) {
        pio = pidx[R_own];
#pragma unroll
        for (int q = 0; q < 3; ++q) {
            ffo[q] = freq[R_own * 3 + q];
            ppo[q] = pres[R_own * 3 + q];
            mmo[q] = rmask[R_own * 3 + q];
        }
    }
    float b2v[8], w30[8], w31[8];
#pragma unroll
    for (int nf = 0; nf < 8; ++nf) {
        b2v[nf] = b2[nf * 16 + ln];
        w30[nf] = W3[(nf * 16 + ln) * 2 + 0];
        w31[nf] = W3[(nf * 16 + ln) * 2 + 1];
    }
    const float b30 = b3[0], b31 = b3[1];

    float lossAcc = 0.f, maskAcc = 0.f;

    for (int s = 0; s < 3; ++s) {
        const int ridx_h = c_perms[pidx_h][s];
        // ---- layer 1 build + gelu + pack into A fragments
        AFrag afr[4];
#pragma unroll
        for (int ks = 0; ks < 4; ++ks) {
            const float* ohp = &W1es[9 + ridx_h][ks * 32 + g * 8];
            f32x4 o0 = *reinterpret_cast<const f32x4*>(ohp);
            f32x4 o1 = *reinterpret_cast<const f32x4*>(ohp + 4);
            float h[8];
#pragma unroll
            for (int j = 0; j < 4; ++j) {
                h[j]     = basef[ks * 8 + j]     + scon[ks * 8 + j]     + o0[j];
                h[4 + j] = basef[ks * 8 + 4 + j] + scon[ks * 8 + 4 + j] + o1[j];
            }
#pragma unroll
            for (int j = 0; j < 8; ++j) afr[ks].h[j] = (__bf16)gelu_fast(h[j]);
        }
        // ---- layer 2: MFMA over K=128
        f32x4 acc[8];
#pragma unroll
        for (int nf = 0; nf < 8; ++nf) acc[nf] = (f32x4){0.f, 0.f, 0.f, 0.f};
#pragma unroll
        for (int ks = 0; ks < 4; ++ks) {
#pragma unroll
            for (int nf = 0; nf < 8; ++nf) {
                const int n = nf * 16 + ln;
                bf16x8 bb = *reinterpret_cast<const bf16x8*>(W2s + n * 256 + ((ks * 64 + g * 16) ^ ((n & 7) << 4)));
                acc[nf] = __builtin_amdgcn_mfma_f32_16x16x32_bf16(afr[ks].v, bb, acc[nf], 0, 0, 0);
            }
        }
        // ---- h2 gelu + layer 3 partials (rows g*4+r, cols nf*16+ln)
        float p0[4] = {0, 0, 0, 0}, p1[4] = {0, 0, 0, 0};
#pragma unroll
        for (int nf = 0; nf < 8; ++nf) {
#pragma unroll
            for (int r = 0; r < 4; ++r) {
                float h2 = gelu_fast(acc[nf][r] + b2v[nf]);
                p0[r] += h2 * w30[nf];
                p1[r] += h2 * w31[nf];
            }
        }
#pragma unroll
        for (int mk = 1; mk < 16; mk <<= 1) {
#pragma unroll
            for (int r = 0; r < 4; ++r) {
                p0[r] += __shfl_xor(p0[r], mk);
                p1[r] += __shfl_xor(p1[r], mk);
            }
        }
        // ---- per-row epilogue on owner lanes (rows g*4 + ln, ln<4)
        if (owner) {
            const int ridx_o = c_perms[pio][s];
            float pf = ((ln == 0) ? p0[0] : (ln == 1) ? p0[1] : (ln == 2) ? p0[2] : p0[3]) + b30;
            float z  = ((ln == 0) ? p1[0] : (ln == 1) ? p1[1] : (ln == 2) ? p1[2] : p1[3]) + b31;
            float gt_f = (ridx_o == 0) ? ffo[0] : (ridx_o == 1) ? ffo[1] : ffo[2];
            float gt_p = (ridx_o == 0) ? ppo[0] : (ridx_o == 1) ? ppo[1] : ppo[2];
            float m    = (ridx_o == 0) ? mmo[0] : (ridx_o == 1) ? mmo[1] : mmo[2];
            float d = pf - gt_f;
            float pl = (fmaxf(z, 0.f) - z * gt_p + __logf(1.0f + __expf(-fabsf(z)))) * m;
            lossAcc += d * d * m + pl;
            maskAcc += m;
            bool msk = m > 0.5f;
            float act_f = msk ? pf : gt_f;
            float act_p = msk ? (1.f / (1.f + __expf(-z))) : gt_p;
            stl[rloc_own][0] = act_f;
            stl[rloc_own][1] = act_p;
            dec_f[R_own * 3 + ridx_o] = act_f;
            dec_p[R_own * 3 + ridx_o] = act_p;
        }
        // ---- incremental state contribution update (same wave: DS ops in order)
        if (s < 2) {
            float af = stl[rowLocal][0];
            float ap = stl[rowLocal][1];
            const float* w0r = &W1es[ridx_h * 3 + 0][0];
            const float* w1r = &W1es[ridx_h * 3 + 1][0];
            const float* w2r = &W1es[ridx_h * 3 + 2][0];
#pragma unroll
            for (int ks = 0; ks < 4; ++ks) {
                const int c0 = ks * 32 + g * 8;
                f32x4 a0 = *reinterpret_cast<const f32x4*>(w0r + c0);
                f32x4 a1 = *reinterpret_cast<const f32x4*>(w0r + c0 + 4);
                f32x4 b0 = *reinterpret_cast<const f32x4*>(w1r + c0);
                f32x4 b1x = *reinterpret_cast<const f32x4*>(w1r + c0 + 4);
                f32x4 c0v = *reinterpret_cast<const f32x4*>(w2r + c0);
                f32x4 c1v = *reinterpret_cast<const f32x4*>(w2r + c0 + 4);
#pragma unroll
                for (int j = 0; j < 4; ++j) {
                    scon[ks * 8 + j]     += af * a0[j] + ap * b0[j]  + c0v[j];
                    scon[ks * 8 + 4 + j] += af * a1[j] + ap * b1x[j] + c1v[j];
                }
            }
        }
    }
    // ---- deterministic loss reduction
#pragma unroll
    for (int mk = 1; mk < 64; mk <<= 1) {
        lossAcc += __shfl_xor(lossAcc, mk);
        maskAcc += __shfl_xor(maskAcc, mk);
    }
    if (lane == 0) { redl[wid * 2] = lossAcc; redl[wid * 2 + 1] = maskAcc; }
    __syncthreads();
    if (t == 0) {
        float ls = 0.f, ms = 0.f;
#pragma unroll
        for (int w = 0; w < 4; ++w) { ls += redl[w * 2]; ms += redl[w * 2 + 1]; }
        partials[2 * (size_t)blockIdx.x]     = ls;
        partials[2 * (size_t)blockIdx.x + 1] = ms;
    }
}

// ---------------- K3: deterministic final reduction ----------------
__global__ __launch_bounds__(256) void k3_reduce(const float* __restrict__ partials,
                                                 int nb, float* __restrict__ out)
{
    __shared__ float sl[256], sm[256];
    int t = threadIdx.x;
    float ls = 0.f, ms = 0.f;
    for (int i = t; i < nb; i += 256) { ls += partials[2 * i]; ms += partials[2 * i + 1]; }
    sl[t] = ls; sm[t] = ms;
    __syncthreads();
    for (int s = 128; s > 0; s >>= 1) {
        if (t < s) { sl[t] += sl[t + s]; sm[t] += sm[t + s]; }
        __syncthreads();
    }
    if (t == 0) out[0] = sl[0] / (sm[0] + 1e-8f);
}

extern "C" void kernel_launch(void* const* d_in, const int* in_sizes, int n_in,
                              void* d_out, int out_size, void* d_ws, size_t ws_size,
                              hipStream_t stream) {
    const float* seq   = (const float*)d_in[0];
    const float* freq  = (const float*)d_in[1];
    const float* pres  = (const float*)d_in[2];
    const float* rmask = (const float*)d_in[3];
    const int*   pidx  = (const int*)d_in[4];
    const float* W1    = (const float*)d_in[5];
    const float* b1    = (const float*)d_in[6];
    const float* W2    = (const float*)d_in[7];
    const float* b2    = (const float*)d_in[8];
    const float* W3    = (const float*)d_in[9];
    const float* b3    = (const float*)d_in[10];

    int B = in_sizes[4];
    float* out   = (float*)d_out;
    float* dec_f = out + 1;
    float* dec_p = out + 1 + (size_t)B * 3;

    char* ws = (char*)d_ws;
    float*  partials = (float*)ws;                                   // 16 KB
    ushort* w1t  = (ushort*)(ws + 16384);                            // 256 KB
    ushort* w2t  = (ushort*)(ws + 16384 + 262144);                   // 32 KB
    ushort* base = (ushort*)(ws + 16384 + 262144 + 32768);           // 33.5 MB

    k0_prep<<<(DDIM * HDIM + HDIM * HDIM + 255) / 256, 256, 0, stream>>>(W1, W2, w1t, w2t);
    k1_gemm<<<B / 128, 256, 0, stream>>>(seq, w1t, b1, base);
    k2_steps<<<B / 64, 256, 0, stream>>>(base, w2t, freq, pres, rmask, pidx,
                                         W1, b2, W3, b3, dec_f, dec_p, partials);
    k3_reduce<<<1, 256, 0, stream>>>(partials, B / 64, out);
}